// Round 5
// baseline (186.933 us; speedup 1.0000x reference)
//
#include <hip/hip_runtime.h>

// KAN cubic-spline elementwise: out = id_gain[c]*x + spline(clamp(a[c]*x+b[c])) + bias[c]
// B=32, C=192, H=64, W=64, K=32.  25,165,824 fp32 elems; ~150-200 MB HBM traffic
// -> floor ~24-32 us. R2 was latency-bound (59 us, VALU 36%, HBM 32%):
// 1 outstanding load/wave + per-iter scalar channel loads on the critical path.
// R3/R5: channels cycle with period 3 (512 planes/stride % 192 = 128) -> hoist
// all channel state to prologue; software-pipeline batches of 3 loads.
// R5 fix: __builtin_nontemporal_store needs a clang ext_vector, not HIP float4.

#define NCH     192
#define TOTAL4  6291456               // float4 count
#define BLOCKS  2048
#define TPB     256
#define STRIDE  (BLOCKS * TPB)        // 524288 float4 = 512 planes

typedef float f32x4 __attribute__((ext_vector_type(4)));

__device__ __forceinline__ float kan_elem(float xx, float a_c, float b_c,
                                          float g_c, float s_c, float av) {
    float xa = fmaf(xx, a_c, b_c);
    xa = fminf(fmaxf(xa, -1.5f), 1.5f);
    float u  = fmaf(xa, 15.5f, 15.5f);   // (xa+1) * 0.5*(K-1)
    float fi = floorf(u);
    int   i  = (int)fi;
    float t  = u - fi;                   // in [0,1)
    int i0 = min(max(i - 1, 0), 31);
    int i1 = min(max(i,     0), 31);
    int i2 = min(max(i + 1, 0), 31);
    int i3 = min(max(i + 2, 0), 31);
    // lane L holds alpha[c][L&31]; data-dependent taps via ds_bpermute crossbar
    float p0 = __shfl(av, i0, 64);
    float p1 = __shfl(av, i1, 64);
    float p2 = __shfl(av, i2, 64);
    float p3 = __shfl(av, i3, 64);
    float s  = 1.0f - t;
    float t2 = t * t, s2 = s * s;
    const float k6 = 1.0f / 6.0f;
    float w0 = s2 * s * k6;              // (1-t)^3/6
    float w3 = t2 * t * k6;              // t^3/6
    float w1 = fmaf(t2, fmaf(t, 0.5f, -1.0f), 2.0f / 3.0f);  // (4-6t^2+3t^3)/6
    float w2 = fmaf(s2, fmaf(s, 0.5f, -1.0f), 2.0f / 3.0f);  // symmetric in s
    float spline = fmaf(p0, w0, fmaf(p1, w1, fmaf(p2, w2, p3 * w3)));
    return fmaf(g_c, xx, spline + s_c);
}

__device__ __forceinline__ f32x4 kan4(f32x4 xv, float a_c, float b_c,
                                      float g_c, float s_c, float av) {
    f32x4 ov;
    ov.x = kan_elem(xv.x, a_c, b_c, g_c, s_c, av);
    ov.y = kan_elem(xv.y, a_c, b_c, g_c, s_c, av);
    ov.z = kan_elem(xv.z, a_c, b_c, g_c, s_c, av);
    ov.w = kan_elem(xv.w, a_c, b_c, g_c, s_c, av);
    return ov;
}

__global__ __launch_bounds__(TPB) void kan_cubic_kernel(
    const float* __restrict__ x, const float* __restrict__ a,
    const float* __restrict__ b, const float* __restrict__ alpha,
    const float* __restrict__ id_gain, const float* __restrict__ bias,
    float* __restrict__ out)
{
    const int j  = threadIdx.x & 31;               // alpha column this lane holds
    const int g0 = blockIdx.x * TPB + threadIdx.x; // wave-aligned; plane-uniform per wave

    // 12 iterations/thread; plane advances 512/iter; 512 % 192 = 128 -> channel
    // sequence has period 3: c0, c0+128, c0+64 (mod 192). Hoist all channel state.
    int c0 = __builtin_amdgcn_readfirstlane((g0 >> 10) % NCH);
    int c1 = c0 + 128; if (c1 >= NCH) c1 -= NCH;
    int c2 = c0 + 64;  if (c2 >= NCH) c2 -= NCH;

    float a0c = a[c0], b0c = b[c0], g0c = id_gain[c0], s0c = bias[c0];
    float a1c = a[c1], b1c = b[c1], g1c = id_gain[c1], s1c = bias[c1];
    float a2c = a[c2], b2c = b[c2], g2c = id_gain[c2], s2c = bias[c2];
    float av0 = alpha[(c0 << 5) + j];
    float av1 = alpha[(c1 << 5) + j];
    float av2 = alpha[(c2 << 5) + j];

    const f32x4* __restrict__ x4 = reinterpret_cast<const f32x4*>(x);
    f32x4* __restrict__ o4 = reinterpret_cast<f32x4*>(out);

    // software pipeline: 4 batches x 3 float4, next batch's loads in flight
    // while computing the current one (3 outstanding 1KB loads per wave).
    f32x4 v0 = x4[g0 + 0 * STRIDE];
    f32x4 v1 = x4[g0 + 1 * STRIDE];
    f32x4 v2 = x4[g0 + 2 * STRIDE];

    #pragma unroll
    for (int bb = 0; bb < 4; ++bb) {
        f32x4 n0, n1, n2;
        if (bb < 3) {
            n0 = x4[g0 + (3 * bb + 3) * STRIDE];
            n1 = x4[g0 + (3 * bb + 4) * STRIDE];
            n2 = x4[g0 + (3 * bb + 5) * STRIDE];
        } else {
            n0 = v0; n1 = v1; n2 = v2;   // dead in last iter, keeps defs valid
        }
        f32x4 r0 = kan4(v0, a0c, b0c, g0c, s0c, av0);
        f32x4 r1 = kan4(v1, a1c, b1c, g1c, s1c, av1);
        f32x4 r2 = kan4(v2, a2c, b2c, g2c, s2c, av2);
        // out is never re-read: nontemporal stores keep x resident in L2/L3
        __builtin_nontemporal_store(r0, &o4[g0 + (3 * bb + 0) * STRIDE]);
        __builtin_nontemporal_store(r1, &o4[g0 + (3 * bb + 1) * STRIDE]);
        __builtin_nontemporal_store(r2, &o4[g0 + (3 * bb + 2) * STRIDE]);
        v0 = n0; v1 = n1; v2 = n2;
    }
}

extern "C" void kernel_launch(void* const* d_in, const int* in_sizes, int n_in,
                              void* d_out, int out_size, void* d_ws, size_t ws_size,
                              hipStream_t stream) {
    const float* x       = (const float*)d_in[0];
    const float* a       = (const float*)d_in[1];
    const float* b       = (const float*)d_in[2];
    const float* alpha   = (const float*)d_in[3];
    const float* id_gain = (const float*)d_in[4];
    const float* bias    = (const float*)d_in[5];
    float* out = (float*)d_out;
    kan_cubic_kernel<<<BLOCKS, TPB, 0, stream>>>(x, a, b, alpha, id_gain, bias, out);
}